// Round 1
// 1031.827 us; speedup vs baseline: 1.1635x; 1.1635x over previous
//
#include <hip/hip_runtime.h>
#include <hip/hip_bf16.h>
#include <stdint.h>

#define HD   1024
#define BB   64
#define SS   2048
#define MT   (BB*SS)          // 131072 rows
#define NEGV -10000000000.0f

typedef __attribute__((ext_vector_type(8))) short bf16x8;
typedef __attribute__((ext_vector_type(4))) float f32x4;
typedef __attribute__((ext_vector_type(4))) int   i32x4;

__device__ __forceinline__ void gll16(const void* g, void* l) {
  __builtin_amdgcn_global_load_lds((const __attribute__((address_space(1))) void*)g,
                                   (__attribute__((address_space(3))) void*)l, 16, 0, 0);
}

// tanh via native exp + v_rcp_f32 (1-ulp approx): 1 - 2/(e^{2x}+1).
// Saturates correctly at +/-1 for large |x| (rcp(inf)=0, rcp(1)=1).
__device__ __forceinline__ float tanh_fast(float x) {
  float e = __expf(2.0f * x);
  return 1.0f - 2.0f * __builtin_amdgcn_rcpf(e + 1.0f);
}

// ---------------------------------------------------------------------------
// Tiled+swizzled bf16 layout (shared by A and B):
//   tile (t, kc) is 8192 contiguous bf16 (16 KB):
//     out[tilebase + l*64 + j*8 + e] = src[row = t*128 + l][k = kc*64 + (j^(l&7))*8 + e]
// GEMM stages a tile with linear global_load_lds; fragment reads
// (8 consecutive k per lane) land 2-way bank aliased (free).
// ---------------------------------------------------------------------------

// Kernel 1a: re-tile We = W_attn[H:2H]^T into that layout (transposed: "row"=n col)
__global__ void prep_we(const float* __restrict__ Wattn, __hip_bfloat16* __restrict__ out) {
  __shared__ float st[64][132];
  int tid = threadIdx.x;
  int nt = blockIdx.x >> 4, kc = blockIdx.x & 15;
  const float* src = Wattn + (size_t)(HD + kc*64)*HD + nt*128;
  #pragma unroll 4
  for (int i = 0; i < 32; ++i) {
    int s = i*256 + tid;
    int kk = s >> 7, nn = s & 127;
    st[kk][nn] = src[(size_t)kk*HD + nn];
  }
  __syncthreads();
  size_t base = (size_t)blockIdx.x * 8192;
  #pragma unroll 4
  for (int i = 0; i < 32; ++i) {
    int lin = i*256 + tid;
    int nl = lin >> 6, j = (lin >> 3) & 7, e = lin & 7;
    int kk = ((j ^ (nl & 7)) << 3) + e;
    out[base + lin] = __float2bfloat16(st[kk][nl]);
  }
}

// Kernel 1b: convert E (fp32 row-major) into the tiled bf16 layout (no transpose).
__global__ void prep_E(const float* __restrict__ E, __hip_bfloat16* __restrict__ out) {
  int tid = threadIdx.x;
  int mt = blockIdx.x >> 4, kc = blockIdx.x & 15;
  const float* src = E + ((size_t)mt*128)*HD + kc*64;
  __hip_bfloat16* dst = out + (size_t)blockIdx.x * 8192;
  #pragma unroll
  for (int i = 0; i < 4; ++i) {
    int u = i*256 + tid;
    int ml = u >> 3, j = u & 7;
    int sk = ((j ^ (ml & 7)) << 3);
    const float* p = src + (size_t)ml*HD + sk;
    f32x4 v0 = *(const f32x4*)p;
    f32x4 v1 = *(const f32x4*)(p + 4);
    union { __hip_bfloat162 h[4]; i32x4 q; } cv;
    cv.h[0] = __float22bfloat162_rn(make_float2(v0.x, v0.y));
    cv.h[1] = __float22bfloat162_rn(make_float2(v0.z, v0.w));
    cv.h[2] = __float22bfloat162_rn(make_float2(v1.x, v1.y));
    cv.h[3] = __float22bfloat162_rn(make_float2(v1.z, v1.w));
    *(i32x4*)(dst + (size_t)u*8) = cv.q;
  }
}

// ---------------------------------------------------------------------------
// Kernel 2: dpb[b][n] = b_attn[n] + sum_h dec[b][h] * Wd[h][n]   (all fp32)
// ---------------------------------------------------------------------------
__global__ void prep_dpb(const float* __restrict__ dec, const float* __restrict__ Wattn,
                         const float* __restrict__ battn, float* __restrict__ dpb) {
  __shared__ float red[4][64];
  int b = blockIdx.y, n0 = blockIdx.x*64;
  int nn = threadIdx.x & 63, kg = threadIdx.x >> 6;
  const float* wp = Wattn + (size_t)(kg*256)*HD + n0 + nn;
  const float* dp = dec + b*HD + kg*256;
  float acc = 0.0f;
  #pragma unroll 8
  for (int h = 0; h < 256; ++h) acc += dp[h] * wp[(size_t)h*HD];
  red[kg][nn] = acc;
  __syncthreads();
  if (threadIdx.x < 64) {
    int n = n0 + threadIdx.x;
    dpb[b*HD + n] = battn[n] + red[0][threadIdx.x] + red[1][threadIdx.x]
                             + red[2][threadIdx.x] + red[3][threadIdx.x];
  }
}

// ---------------------------------------------------------------------------
// Kernel 3 (fast): 256x256 8-phase GEMM C = E@We, BK=64, 512 thr (8 waves 2x4),
// double-buffered 128 KiB LDS, counted vmcnt(6), setprio around MFMA clusters.
// Fused epilogue: tanh(C + dpb) . v_w -> atomicAdd logits.
//
// Per K-tile t (buf = t&1), 4 phases; quadrant order (hr,hc) = 00,01,11,10.
//   slot free order: A0 after ph1, B1 after ph2, A1 after ph3, B0 after ph4.
//   stage pairing (into slot freed previous phase):
//     ph1: (t+1)B0   ph2: (t+2)A0   ph3: (t+2)B1   ph4: (t+2)A1
//   issue order per tile tau: A0,B1,A1,B0 -> vmcnt(6) at ph4 guarantees tile
//   t+1 fully landed (last 3 halves in flight = (t+2)A0,B1,A1).
//   Guards skip stages for tiles >= 16; at t=14 the pipeline shortens, so ph4
//   uses vmcnt(0) there (t>=14) to cover tile 15's B1/A1/B0.
// ---------------------------------------------------------------------------
__global__ void __launch_bounds__(512, 2) gemm_fused_8ph(
    const __hip_bfloat16* __restrict__ At, const __hip_bfloat16* __restrict__ Wt,
    const float* __restrict__ dpb, const float* __restrict__ vw,
    float* __restrict__ logits) {
  __shared__ __align__(16) char lds[131072];   // [buf:2][op:2(A,B)][half:2][16KB]

  int tid = threadIdx.x;
  int lane = tid & 63, wid = tid >> 6;
  int wm = wid & 1, wn = wid >> 1;              // 2 x 4 wave grid
  int lane15 = lane & 15, kg = lane >> 4;

  // XCD-aware decode: 2048 blocks = 8 xcd * (64 bm * 4 bn), bn fastest.
  int x = blockIdx.x & 7, r = blockIdx.x >> 3;
  int bm = x*64 + (r >> 2);                     // 0..511
  int bn = r & 3;                               // 0..3

  f32x4 acc[2][2][4][2];                        // [hr][hc][mf][nf]
  #pragma unroll
  for (int i = 0; i < 2; ++i)
    #pragma unroll
    for (int j = 0; j < 2; ++j)
      #pragma unroll
      for (int k = 0; k < 4; ++k)
        #pragma unroll
        for (int l = 0; l < 2; ++l)
          acc[i][j][k][l] = (f32x4){0.f, 0.f, 0.f, 0.f};

  bf16x8 af[4][2], bfr[2][2];

  // stage one half-tile (16 KB): op 0=A 1=B, half h, K-tile t. 2 gll16/thread.
  auto stage = [&](int op, int h, int t) {
    const char* g = op ? ((const char*)Wt + (((size_t)(bn*2 + h)*16 + t) << 14))
                       : ((const char*)At + (((size_t)(bm*2 + h)*16 + t) << 14));
    char* l = lds + ((t & 1) << 16) + (op << 15) + (h << 14);
    gll16(g + (size_t)(wid*64 + lane)*16,     l + wid*1024);
    gll16(g + (size_t)((8+wid)*64 + lane)*16, l + (8+wid)*1024);
  };
  auto readA = [&](int hr, int t) {             // 8 x ds_read_b128
    const char* b = lds + ((t & 1) << 16) + (hr << 14);
    #pragma unroll
    for (int mf = 0; mf < 4; ++mf) {
      int ll = wm*64 + mf*16 + lane15;
      const char* rp = b + ll*128;
      int sw = (ll & 7) << 4;
      af[mf][0] = *(const bf16x8*)(rp + ((kg << 4) ^ sw));
      af[mf][1] = *(const bf16x8*)(rp + (((4 + kg) << 4) ^ sw));
    }
  };
  auto readB = [&](int hc, int t) {             // 4 x ds_read_b128
    const char* b = lds + ((t & 1) << 16) + 32768 + (hc << 14);
    #pragma unroll
    for (int nf = 0; nf < 2; ++nf) {
      int ll = wn*32 + nf*16 + lane15;
      const char* rp = b + ll*128;
      int sw = (ll & 7) << 4;
      bfr[nf][0] = *(const bf16x8*)(rp + ((kg << 4) ^ sw));
      bfr[nf][1] = *(const bf16x8*)(rp + (((4 + kg) << 4) ^ sw));
    }
  };

#define MFMA_PH(HR, HC) do {                                                   \
    __builtin_amdgcn_s_setprio(1);                                             \
    _Pragma("unroll")                                                          \
    for (int kk = 0; kk < 2; ++kk)                                             \
      _Pragma("unroll")                                                        \
      for (int mf = 0; mf < 4; ++mf)                                           \
        _Pragma("unroll")                                                      \
        for (int nf = 0; nf < 2; ++nf)                                         \
          acc[HR][HC][mf][nf] = __builtin_amdgcn_mfma_f32_16x16x32_bf16(       \
              af[mf][kk], bfr[nf][kk], acc[HR][HC][mf][nf], 0, 0, 0);          \
    __builtin_amdgcn_s_setprio(0);                                             \
    __builtin_amdgcn_sched_barrier(0);                                         \
  } while (0)

#define PH_SYNC() do {                                                         \
    __builtin_amdgcn_s_barrier();                                              \
    asm volatile("s_waitcnt lgkmcnt(0)");                                      \
    __builtin_amdgcn_sched_barrier(0);                                         \
  } while (0)

  // Prologue: t0 {A0,B1,A1,B0}, t1 {A0,B1,A1} (t1 B0 staged at t0.ph1).
  stage(0, 0, 0); stage(1, 1, 0); stage(0, 1, 0); stage(1, 0, 0);
  stage(0, 0, 1); stage(1, 1, 1); stage(0, 1, 1);
  asm volatile("s_waitcnt vmcnt(6)" ::: "memory");   // t0 fully landed
  __builtin_amdgcn_s_barrier();

  #pragma unroll 2
  for (int t = 0; t < 16; ++t) {
    // -------- PH1: quad (0,0); reads A0,B0; stage (t+1)B0 --------
    readA(0, t); readB(0, t);
    if (t + 1 < 16) stage(1, 0, t + 1);
    asm volatile("s_waitcnt lgkmcnt(8)");            // partial drain (12 reads)
    PH_SYNC();
    MFMA_PH(0, 0);
    __builtin_amdgcn_s_barrier();

    // -------- PH2: quad (0,1); reads B1 (A cached); stage (t+2)A0 --------
    readB(1, t);
    if (t + 2 < 16) stage(0, 0, t + 2);
    PH_SYNC();
    MFMA_PH(0, 1);
    __builtin_amdgcn_s_barrier();

    // -------- PH3: quad (1,1); reads A1 (B cached); stage (t+2)B1 --------
    readA(1, t);
    if (t + 2 < 16) stage(1, 1, t + 2);
    PH_SYNC();
    MFMA_PH(1, 1);
    __builtin_amdgcn_s_barrier();

    // -------- PH4: quad (1,0); reads B0; stage (t+2)A1 --------
    readB(0, t);
    if (t + 2 < 16) stage(0, 1, t + 2);
    PH_SYNC();
    MFMA_PH(1, 0);
    if (t < 14) asm volatile("s_waitcnt vmcnt(6)" ::: "memory");
    else        asm volatile("s_waitcnt vmcnt(0)" ::: "memory");
    __builtin_amdgcn_s_barrier();
  }
#undef MFMA_PH
#undef PH_SYNC

  // -------- fused epilogue: tanh(C + dpb) . vw, reduce over n --------
  __syncthreads();
  float* red = (float*)lds;                     // alias tile LDS (all reads done)
  if (tid < 256) red[tid] = 0.0f;
  __syncthreads();

  int m0 = bm << 8, n0 = bn << 8;
  int bidx = m0 >> 11;                          // 256-row block within one batch
  float dpv[2][2], vwv[2][2];
  #pragma unroll
  for (int hc = 0; hc < 2; ++hc)
    #pragma unroll
    for (int nf = 0; nf < 2; ++nf) {
      int n = n0 + hc*128 + wn*32 + nf*16 + lane15;
      dpv[hc][nf] = dpb[bidx*HD + n];
      vwv[hc][nf] = vw[n];
    }

  #pragma unroll
  for (int hr = 0; hr < 2; ++hr)
    #pragma unroll
    for (int mf = 0; mf < 4; ++mf)
      #pragma unroll
      for (int rr = 0; rr < 4; ++rr) {
        float s = 0.0f;
        #pragma unroll
        for (int hc = 0; hc < 2; ++hc)
          #pragma unroll
          for (int nf = 0; nf < 2; ++nf)
            s += tanh_fast(acc[hr][hc][mf][nf][rr] + dpv[hc][nf]) * vwv[hc][nf];
        s += __shfl_xor(s, 1); s += __shfl_xor(s, 2);
        s += __shfl_xor(s, 4); s += __shfl_xor(s, 8);
        if (lane15 == 0) atomicAdd(&red[hr*128 + wm*64 + mf*16 + kg*4 + rr], s);
      }
  __syncthreads();
  if (tid < 256) atomicAdd(&logits[m0 + tid], red[tid]);
}

// ---------------------------------------------------------------------------
// XCD-aware decode for the 8192-block fallback GEMM.
// ---------------------------------------------------------------------------
__device__ __forceinline__ void decode_bid(int bid, int& bm, int& bn) {
  int x = bid & 7, r = bid >> 3;
  bm = x*128 + (r >> 3);
  bn = r & 7;
}

// ---------------------------------------------------------------------------
// Kernel 3 (fallback, ws too small): fp32 A staged via VGPR cvt (128^2 path).
// ---------------------------------------------------------------------------
__global__ void __launch_bounds__(256) gemm_fused_f32(
    const float* __restrict__ E, const __hip_bfloat16* __restrict__ Wt,
    const float* __restrict__ dpb, const float* __restrict__ vw,
    float* __restrict__ logits) {
  __shared__ __align__(16) short Al[128*72];
  __shared__ __align__(16) short Bl[128*64];
  __shared__ float red[128];

  int tid = threadIdx.x;
  int lane = tid & 63, wid = tid >> 6;
  int wm = wid & 1, wn = wid >> 1;
  int bm, bn; decode_bid(blockIdx.x, bm, bn);
  int m0 = bm << 7, n0 = bn << 7;
  int lane15 = lane & 15, kg = lane >> 4;

  f32x4 acc[4][4];
  #pragma unroll
  for (int a = 0; a < 4; ++a)
    #pragma unroll
    for (int c = 0; c < 4; ++c) acc[a][c] = (f32x4){0.f, 0.f, 0.f, 0.f};

  for (int kc = 0; kc < 16; ++kc) {
    const char* bt = (const char*)Wt + ((size_t)(bn*16 + kc) * 8192) * 2;
    #pragma unroll
    for (int i = 0; i < 4; ++i) {
      int segbase = (wid*4 + i) * 64;
      gll16(bt + (size_t)(segbase + lane)*16, (char*)Bl + segbase*16);
    }
    const float* Eg = E + (m0*HD + kc*64);
    #pragma unroll
    for (int i = 0; i < 8; ++i) {
      int s = i*256 + tid;
      int r = s >> 4, q = s & 15;
      f32x4 v = *(const f32x4*)(Eg + r*HD + q*4);
      union { __hip_bfloat162 h[2]; unsigned long long u; } cv;
      cv.h[0] = __float22bfloat162_rn(make_float2(v.x, v.y));
      cv.h[1] = __float22bfloat162_rn(make_float2(v.z, v.w));
      *(unsigned long long*)&Al[r*72 + q*4] = cv.u;
    }
    __syncthreads();
    #pragma unroll
    for (int kh = 0; kh < 2; ++kh) {
      bf16x8 af[4], bfr[4];
      #pragma unroll
      for (int mf = 0; mf < 4; ++mf) {
        int row = wm*64 + mf*16 + lane15;
        af[mf] = *(const bf16x8*)&Al[row*72 + kh*32 + kg*8];
      }
      #pragma unroll
      for (int nf = 0; nf < 4; ++nf) {
        int nl = wn*64 + nf*16 + lane15;
        int jj = kh*4 + kg;
        bfr[nf] = *(const bf16x8*)&Bl[nl*64 + ((jj ^ (nl & 7)) << 3)];
      }
      #pragma unroll
      for (int mf = 0; mf < 4; ++mf)
        #pragma unroll
        for (int nf = 0; nf < 4; ++nf)
          acc[mf][nf] = __builtin_amdgcn_mfma_f32_16x16x32_bf16(af[mf], bfr[nf], acc[mf][nf], 0, 0, 0);
    }
    __syncthreads();
  }

  int bidx = m0 >> 11;
  float dpv[4], vwv[4];
  #pragma unroll
  for (int nf = 0; nf < 4; ++nf) {
    int n = n0 + wn*64 + nf*16 + lane15;
    dpv[nf] = dpb[bidx*HD + n];
    vwv[nf] = vw[n];
  }
  if (tid < 128) red[tid] = 0.0f;
  __syncthreads();
  #pragma unroll
  for (int mf = 0; mf < 4; ++mf) {
    #pragma unroll
    for (int r = 0; r < 4; ++r) {
      float s = 0.0f;
      #pragma unroll
      for (int nf = 0; nf < 4; ++nf) {
        float x = acc[mf][nf][r] + dpv[nf];
        s += tanh_fast(x) * vwv[nf];
      }
      s += __shfl_xor(s, 1); s += __shfl_xor(s, 2);
      s += __shfl_xor(s, 4); s += __shfl_xor(s, 8);
      if (lane15 == 0) atomicAdd(&red[wm*64 + mf*16 + kg*4 + r], s);
    }
  }
  __syncthreads();
  if (tid < 128) atomicAdd(&logits[m0 + tid], red[tid]);
}

// ---------------------------------------------------------------------------
// Kernel 4: masked softmax over S per batch row.  mask==1 -> -1e10
// ---------------------------------------------------------------------------
__global__ void softmax_k(const float* __restrict__ logits, const int* __restrict__ mask,
                          float* __restrict__ out) {
  __shared__ float smax[4];
  __shared__ float ssum[4];
  int tid = threadIdx.x, lane = tid & 63, wid = tid >> 6;
  int b = blockIdx.x;
  const float* lg = logits + b*SS;
  const int*   mk = mask   + b*SS;
  f32x4 l0 = *(const f32x4*)(lg + tid*8);
  f32x4 l1 = *(const f32x4*)(lg + tid*8 + 4);
  i32x4 q0 = *(const i32x4*)(mk + tid*8);
  i32x4 q1 = *(const i32x4*)(mk + tid*8 + 4);
  float v[8];
  v[0] = (q0.x == 1) ? NEGV : l0.x;  v[1] = (q0.y == 1) ? NEGV : l0.y;
  v[2] = (q0.z == 1) ? NEGV : l0.z;  v[3] = (q0.w == 1) ? NEGV : l0.w;
  v[4] = (q1.x == 1) ? NEGV : l1.x;  v[5] = (q1.y == 1) ? NEGV : l1.y;
  v[6] = (q1.z == 1) ? NEGV : l1.z;  v[7] = (q1.w == 1) ? NEGV : l1.w;
  float mx = v[0];
  #pragma unroll
  for (int i = 1; i < 8; ++i) mx = fmaxf(mx, v[i]);
  #pragma unroll
  for (int m = 1; m <= 32; m <<= 1) mx = fmaxf(mx, __shfl_xor(mx, m));
  if (lane == 0) smax[wid] = mx;
  __syncthreads();
  mx = fmaxf(fmaxf(smax[0], smax[1]), fmaxf(smax[2], smax[3]));
  float s = 0.0f;
  #pragma unroll
  for (int i = 0; i < 8; ++i) { v[i] = __expf(v[i] - mx); s += v[i]; }
  #pragma unroll
  for (int m = 1; m <= 32; m <<= 1) s += __shfl_xor(s, m);
  if (lane == 0) ssum[wid] = s;
  __syncthreads();
  s = ssum[0] + ssum[1] + ssum[2] + ssum[3];
  float inv = 1.0f / s;
  f32x4 o0 = {v[0]*inv, v[1]*inv, v[2]*inv, v[3]*inv};
  f32x4 o1 = {v[4]*inv, v[5]*inv, v[6]*inv, v[7]*inv};
  *(f32x4*)(out + b*SS + tid*8)     = o0;
  *(f32x4*)(out + b*SS + tid*8 + 4) = o1;
}

// ---------------------------------------------------------------------------
extern "C" void kernel_launch(void* const* d_in, const int* in_sizes, int n_in,
                              void* d_out, int out_size, void* d_ws, size_t ws_size,
                              hipStream_t stream) {
  const float* dec   = (const float*)d_in[0];   // (B, H)
  const float* enc   = (const float*)d_in[1];   // (B, S, H)
  const int*   mask  = (const int*)  d_in[2];   // (B, S)
  const float* Wattn = (const float*)d_in[3];   // (2H, H)
  const float* battn = (const float*)d_in[4];   // (H)
  const float* vw    = (const float*)d_in[5];   // (H)
  float* out = (float*)d_out;

  const size_t EBF_BYTES = (size_t)MT * HD * 2;             // 268435456
  const size_t FAST_NEED = EBF_BYTES + (2u<<20) + (256u<<10) + (512u<<10);

  char* ws = (char*)d_ws;
  if (ws_size >= FAST_NEED) {
    __hip_bfloat16* ebf = (__hip_bfloat16*)ws;
    __hip_bfloat16* wet = (__hip_bfloat16*)(ws + EBF_BYTES);
    float* dpb    = (float*)(ws + EBF_BYTES + (2u<<20));
    float* logits = (float*)(ws + EBF_BYTES + (2u<<20) + (256u<<10));

    prep_E <<<16384, 256, 0, stream>>>(enc, ebf);
    prep_we<<<128, 256, 0, stream>>>(Wattn, wet);
    prep_dpb<<<dim3(16, 64), 256, 0, stream>>>(dec, Wattn, battn, dpb);
    hipMemsetAsync(logits, 0, (size_t)MT*sizeof(float), stream);
    gemm_fused_8ph<<<2048, 512, 0, stream>>>(ebf, wet, dpb, vw, logits);
    softmax_k<<<BB, 256, 0, stream>>>(logits, mask, out);
  } else {
    __hip_bfloat16* wet = (__hip_bfloat16*)ws;
    float* dpb    = (float*)(ws + (2u<<20));
    float* logits = (float*)(ws + (2u<<20) + (256u<<10));

    prep_we<<<128, 256, 0, stream>>>(Wattn, wet);
    prep_dpb<<<dim3(16, 64), 256, 0, stream>>>(dec, Wattn, battn, dpb);
    hipMemsetAsync(logits, 0, (size_t)MT*sizeof(float), stream);
    gemm_fused_f32<<<8192, 256, 0, stream>>>(enc, wet, dpb, vw, logits);
    softmax_k<<<BB, 256, 0, stream>>>(logits, mask, out);
  }
}

// Round 2
// 1028.340 us; speedup vs baseline: 1.1674x; 1.0034x over previous
//
#include <hip/hip_runtime.h>
#include <hip/hip_bf16.h>
#include <stdint.h>

#define HD   1024
#define BB   64
#define SS   2048
#define MT   (BB*SS)          // 131072 rows
#define NEGV -10000000000.0f

typedef __attribute__((ext_vector_type(8))) short bf16x8;
typedef __attribute__((ext_vector_type(4))) float f32x4;
typedef __attribute__((ext_vector_type(4))) int   i32x4;

__device__ __forceinline__ void gll16(const void* g, void* l) {
  __builtin_amdgcn_global_load_lds((const __attribute__((address_space(1))) void*)g,
                                   (__attribute__((address_space(3))) void*)l, 16, 0, 0);
}

// tanh via native exp + v_rcp_f32 (1-ulp approx): 1 - 2/(e^{2x}+1).
__device__ __forceinline__ float tanh_fast(float x) {
  float e = __expf(2.0f * x);
  return 1.0f - 2.0f * __builtin_amdgcn_rcpf(e + 1.0f);
}

// ---------------------------------------------------------------------------
// Tiled+swizzled bf16 layout (shared by A and B):
//   tile (t, kc) is 8192 contiguous bf16 (16 KB):
//     out[tilebase + l*64 + j*8 + e] = src[row = t*128 + l][k = kc*64 + (j^(l&7))*8 + e]
// GEMM stages a tile with linear global_load_lds; fragment reads
// (8 consecutive k per lane) land 2-way bank aliased (free).
// ---------------------------------------------------------------------------

// ---------------------------------------------------------------------------
// Fused prep kernel: one dispatch does all pre-GEMM work.
//   blocks [0, nE)              : prep_E  (E fp32 -> tiled bf16), nE = 16384
//   blocks [nE, nE+128)         : prep_we (We^T -> tiled bf16)
//   blocks [nE+128, nE+1152)    : prep_dpb (dec@Wd + b_attn)
//   blocks [nE+1152, nE+1280)   : zero logits (replaces hipMemsetAsync)
// Fallback path calls with nE = 0.
// ---------------------------------------------------------------------------
__global__ void __launch_bounds__(256) prep_all(
    int nE,
    const float* __restrict__ enc, __hip_bfloat16* __restrict__ ebf,
    const float* __restrict__ Wattn, __hip_bfloat16* __restrict__ wet,
    const float* __restrict__ dec, const float* __restrict__ battn,
    float* __restrict__ dpb, float* __restrict__ logits) {
  __shared__ float red[4][64];
  int tid = threadIdx.x;
  int bid = blockIdx.x;

  if (bid < nE) {
    // ---- prep_E: 8 rows per block, fully-coalesced 2KB/wave reads, ----
    // ---- write-side swizzle (permuted 16B stores within 128B windows) ----
    int mt = bid >> 4;                   // 128-row tile index
    int l_base = (bid & 15) * 8;         // row-in-tile base
    const float* src = enc + ((size_t)bid * 8) * HD;
    #pragma unroll
    for (int i = 0; i < 4; ++i) {
      int unit = i*256 + tid;            // 0..1023 = (row r, 8-elem chunk j128)
      int r = unit >> 7;                 // 0..7
      int j128 = unit & 127;             // k-chunk within row
      int kc = j128 >> 3, jj = j128 & 7;
      int l = l_base + r;
      int jd = jj ^ (l & 7);
      const float* p = src + (size_t)r*HD + j128*8;
      f32x4 v0 = *(const f32x4*)p;
      f32x4 v1 = *(const f32x4*)(p + 4);
      union { __hip_bfloat162 h[4]; i32x4 q; } cv;
      cv.h[0] = __float22bfloat162_rn(make_float2(v0.x, v0.y));
      cv.h[1] = __float22bfloat162_rn(make_float2(v0.z, v0.w));
      cv.h[2] = __float22bfloat162_rn(make_float2(v1.x, v1.y));
      cv.h[3] = __float22bfloat162_rn(make_float2(v1.z, v1.w));
      *(i32x4*)(ebf + ((size_t)(mt*16 + kc))*8192 + l*64 + jd*8) = cv.q;
    }
    return;
  }
  bid -= nE;

  if (bid < 128) {
    // ---- prep_we: direct (no LDS) transpose re-tile; W is L2-resident ----
    int nt = bid >> 4, kc = bid & 15;
    const float* src = Wattn + (size_t)(HD + kc*64)*HD + nt*128;
    size_t base = (size_t)bid * 8192;
    #pragma unroll 4
    for (int i = 0; i < 32; ++i) {
      int lin = i*256 + tid;
      int nl = lin >> 6, j = (lin >> 3) & 7, e = lin & 7;
      int kk = ((j ^ (nl & 7)) << 3) + e;
      wet[base + lin] = __float2bfloat16(src[(size_t)kk*HD + nl]);
    }
    return;
  }
  bid -= 128;

  if (bid < 1024) {
    // ---- prep_dpb: dpb[b][n] = b_attn[n] + sum_h dec[b][h]*Wd[h][n] ----
    int b = bid >> 4, n0 = (bid & 15) * 64;
    int nn = tid & 63, kg = tid >> 6;
    const float* wp = Wattn + (size_t)(kg*256)*HD + n0 + nn;
    const float* dp = dec + b*HD + kg*256;
    float acc = 0.0f;
    #pragma unroll 8
    for (int h = 0; h < 256; ++h) acc += dp[h] * wp[(size_t)h*HD];
    red[kg][nn] = acc;
    __syncthreads();
    if (tid < 64) {
      int n = n0 + tid;
      dpb[b*HD + n] = battn[n] + red[0][tid] + red[1][tid]
                               + red[2][tid] + red[3][tid];
    }
    return;
  }
  bid -= 1024;

  // ---- zero logits: 128 blocks x 4KB ----
  f32x4 z = {0.f, 0.f, 0.f, 0.f};
  *(f32x4*)(logits + (size_t)bid*1024 + tid*4) = z;
}

// ---------------------------------------------------------------------------
// Kernel 3 (fast): 256x256 8-phase GEMM C = E@We, BK=64, 512 thr (8 waves 2x4),
// double-buffered 128 KiB LDS, counted vmcnt(6), setprio around MFMA clusters.
// Fused epilogue: tanh(C + dpb) . v_w -> atomicAdd logits.
//
// Per K-tile t (buf = t&1), 4 phases; quadrant order (hr,hc) = 00,01,11,10.
//   slot free order: A0 after ph1, B1 after ph2, A1 after ph3, B0 after ph4.
//   stage pairing: ph1:(t+1)B0  ph2:(t+2)A0  ph3:(t+2)B1  ph4:(t+2)A1
//   vmcnt(6) at ph4 guarantees tile t+1 fully landed.
// ---------------------------------------------------------------------------
__global__ void __launch_bounds__(512, 2) gemm_fused_8ph(
    const __hip_bfloat16* __restrict__ At, const __hip_bfloat16* __restrict__ Wt,
    const float* __restrict__ dpb, const float* __restrict__ vw,
    float* __restrict__ logits) {
  __shared__ __align__(16) char lds[131072];   // [buf:2][op:2(A,B)][half:2][16KB]

  int tid = threadIdx.x;
  int lane = tid & 63, wid = tid >> 6;
  int wm = wid & 1, wn = wid >> 1;              // 2 x 4 wave grid
  int lane15 = lane & 15, kg = lane >> 4;

  // XCD-aware decode: 2048 blocks = 8 xcd * (64 bm * 4 bn), bn fastest.
  int x = blockIdx.x & 7, r = blockIdx.x >> 3;
  int bm = x*64 + (r >> 2);                     // 0..511
  int bn = r & 3;                               // 0..3

  f32x4 acc[2][2][4][2];                        // [hr][hc][mf][nf]
  #pragma unroll
  for (int i = 0; i < 2; ++i)
    #pragma unroll
    for (int j = 0; j < 2; ++j)
      #pragma unroll
      for (int k = 0; k < 4; ++k)
        #pragma unroll
        for (int l = 0; l < 2; ++l)
          acc[i][j][k][l] = (f32x4){0.f, 0.f, 0.f, 0.f};

  bf16x8 af[4][2], bfr[2][2];

  auto stage = [&](int op, int h, int t) {
    const char* g = op ? ((const char*)Wt + (((size_t)(bn*2 + h)*16 + t) << 14))
                       : ((const char*)At + (((size_t)(bm*2 + h)*16 + t) << 14));
    char* l = lds + ((t & 1) << 16) + (op << 15) + (h << 14);
    gll16(g + (size_t)(wid*64 + lane)*16,     l + wid*1024);
    gll16(g + (size_t)((8+wid)*64 + lane)*16, l + (8+wid)*1024);
  };
  auto readA = [&](int hr, int t) {             // 8 x ds_read_b128
    const char* b = lds + ((t & 1) << 16) + (hr << 14);
    #pragma unroll
    for (int mf = 0; mf < 4; ++mf) {
      int ll = wm*64 + mf*16 + lane15;
      const char* rp = b + ll*128;
      int sw = (ll & 7) << 4;
      af[mf][0] = *(const bf16x8*)(rp + ((kg << 4) ^ sw));
      af[mf][1] = *(const bf16x8*)(rp + (((4 + kg) << 4) ^ sw));
    }
  };
  auto readB = [&](int hc, int t) {             // 4 x ds_read_b128
    const char* b = lds + ((t & 1) << 16) + 32768 + (hc << 14);
    #pragma unroll
    for (int nf = 0; nf < 2; ++nf) {
      int ll = wn*32 + nf*16 + lane15;
      const char* rp = b + ll*128;
      int sw = (ll & 7) << 4;
      bfr[nf][0] = *(const bf16x8*)(rp + ((kg << 4) ^ sw));
      bfr[nf][1] = *(const bf16x8*)(rp + (((4 + kg) << 4) ^ sw));
    }
  };

#define MFMA_PH(HR, HC) do {                                                   \
    __builtin_amdgcn_s_setprio(1);                                             \
    _Pragma("unroll")                                                          \
    for (int kk = 0; kk < 2; ++kk)                                             \
      _Pragma("unroll")                                                        \
      for (int mf = 0; mf < 4; ++mf)                                           \
        _Pragma("unroll")                                                      \
        for (int nf = 0; nf < 2; ++nf)                                         \
          acc[HR][HC][mf][nf] = __builtin_amdgcn_mfma_f32_16x16x32_bf16(       \
              af[mf][kk], bfr[nf][kk], acc[HR][HC][mf][nf], 0, 0, 0);          \
    __builtin_amdgcn_s_setprio(0);                                             \
    __builtin_amdgcn_sched_barrier(0);                                         \
  } while (0)

#define PH_SYNC() do {                                                         \
    __builtin_amdgcn_s_barrier();                                              \
    asm volatile("s_waitcnt lgkmcnt(0)");                                      \
    __builtin_amdgcn_sched_barrier(0);                                         \
  } while (0)

  // Prologue: t0 {A0,B1,A1,B0}, t1 {A0,B1,A1} (t1 B0 staged at t0.ph1).
  stage(0, 0, 0); stage(1, 1, 0); stage(0, 1, 0); stage(1, 0, 0);
  stage(0, 0, 1); stage(1, 1, 1); stage(0, 1, 1);
  asm volatile("s_waitcnt vmcnt(6)" ::: "memory");   // t0 fully landed
  __builtin_amdgcn_s_barrier();

  #pragma unroll 2
  for (int t = 0; t < 16; ++t) {
    // -------- PH1: quad (0,0); reads A0,B0; stage (t+1)B0 --------
    readA(0, t); readB(0, t);
    if (t + 1 < 16) stage(1, 0, t + 1);
    asm volatile("s_waitcnt lgkmcnt(8)");            // partial drain (12 reads)
    PH_SYNC();
    MFMA_PH(0, 0);
    __builtin_amdgcn_s_barrier();

    // -------- PH2: quad (0,1); reads B1 (A cached); stage (t+2)A0 --------
    readB(1, t);
    if (t + 2 < 16) stage(0, 0, t + 2);
    PH_SYNC();
    MFMA_PH(0, 1);
    __builtin_amdgcn_s_barrier();

    // -------- PH3: quad (1,1); reads A1 (B cached); stage (t+2)B1 --------
    readA(1, t);
    if (t + 2 < 16) stage(1, 1, t + 2);
    PH_SYNC();
    MFMA_PH(1, 1);
    __builtin_amdgcn_s_barrier();

    // -------- PH4: quad (1,0); reads B0; stage (t+2)A1 --------
    readB(0, t);
    if (t + 2 < 16) stage(0, 1, t + 2);
    PH_SYNC();
    MFMA_PH(1, 0);
    if (t < 14) asm volatile("s_waitcnt vmcnt(6)" ::: "memory");
    else        asm volatile("s_waitcnt vmcnt(0)" ::: "memory");
    __builtin_amdgcn_s_barrier();
  }
#undef MFMA_PH
#undef PH_SYNC

  // -------- fused epilogue: tanh(C + dpb) . vw, reduce over n --------
  __syncthreads();
  float* red = (float*)lds;                     // alias tile LDS (all reads done)
  if (tid < 256) red[tid] = 0.0f;
  __syncthreads();

  int m0 = bm << 8, n0 = bn << 8;
  int bidx = m0 >> 11;                          // batch index
  float dpv[2][2], vwv[2][2];
  #pragma unroll
  for (int hc = 0; hc < 2; ++hc)
    #pragma unroll
    for (int nf = 0; nf < 2; ++nf) {
      int n = n0 + hc*128 + wn*32 + nf*16 + lane15;
      dpv[hc][nf] = dpb[bidx*HD + n];
      vwv[hc][nf] = vw[n];
    }

  #pragma unroll
  for (int hr = 0; hr < 2; ++hr)
    #pragma unroll
    for (int mf = 0; mf < 4; ++mf)
      #pragma unroll
      for (int rr = 0; rr < 4; ++rr) {
        float s = 0.0f;
        #pragma unroll
        for (int hc = 0; hc < 2; ++hc)
          #pragma unroll
          for (int nf = 0; nf < 2; ++nf)
            s += tanh_fast(acc[hr][hc][mf][nf][rr] + dpv[hc][nf]) * vwv[hc][nf];
        s += __shfl_xor(s, 1); s += __shfl_xor(s, 2);
        s += __shfl_xor(s, 4); s += __shfl_xor(s, 8);
        if (lane15 == 0) atomicAdd(&red[hr*128 + wm*64 + mf*16 + kg*4 + rr], s);
      }
  __syncthreads();
  if (tid < 256) atomicAdd(&logits[m0 + tid], red[tid]);
}

// ---------------------------------------------------------------------------
// XCD-aware decode for the 8192-block fallback GEMM.
// ---------------------------------------------------------------------------
__device__ __forceinline__ void decode_bid(int bid, int& bm, int& bn) {
  int x = bid & 7, r = bid >> 3;
  bm = x*128 + (r >> 3);
  bn = r & 7;
}

// ---------------------------------------------------------------------------
// Kernel 3 (fallback, ws too small): fp32 A staged via VGPR cvt (128^2 path).
// ---------------------------------------------------------------------------
__global__ void __launch_bounds__(256) gemm_fused_f32(
    const float* __restrict__ E, const __hip_bfloat16* __restrict__ Wt,
    const float* __restrict__ dpb, const float* __restrict__ vw,
    float* __restrict__ logits) {
  __shared__ __align__(16) short Al[128*72];
  __shared__ __align__(16) short Bl[128*64];
  __shared__ float red[128];

  int tid = threadIdx.x;
  int lane = tid & 63, wid = tid >> 6;
  int wm = wid & 1, wn = wid >> 1;
  int bm, bn; decode_bid(blockIdx.x, bm, bn);
  int m0 = bm << 7, n0 = bn << 7;
  int lane15 = lane & 15, kg = lane >> 4;

  f32x4 acc[4][4];
  #pragma unroll
  for (int a = 0; a < 4; ++a)
    #pragma unroll
    for (int c = 0; c < 4; ++c) acc[a][c] = (f32x4){0.f, 0.f, 0.f, 0.f};

  for (int kc = 0; kc < 16; ++kc) {
    const char* bt = (const char*)Wt + ((size_t)(bn*16 + kc) * 8192) * 2;
    #pragma unroll
    for (int i = 0; i < 4; ++i) {
      int segbase = (wid*4 + i) * 64;
      gll16(bt + (size_t)(segbase + lane)*16, (char*)Bl + segbase*16);
    }
    const float* Eg = E + (m0*HD + kc*64);
    #pragma unroll
    for (int i = 0; i < 8; ++i) {
      int s = i*256 + tid;
      int r = s >> 4, q = s & 15;
      f32x4 v = *(const f32x4*)(Eg + r*HD + q*4);
      union { __hip_bfloat162 h[2]; unsigned long long u; } cv;
      cv.h[0] = __float22bfloat162_rn(make_float2(v.x, v.y));
      cv.h[1] = __float22bfloat162_rn(make_float2(v.z, v.w));
      *(unsigned long long*)&Al[r*72 + q*4] = cv.u;
    }
    __syncthreads();
    #pragma unroll
    for (int kh = 0; kh < 2; ++kh) {
      bf16x8 af[4], bfr[4];
      #pragma unroll
      for (int mf = 0; mf < 4; ++mf) {
        int row = wm*64 + mf*16 + lane15;
        af[mf] = *(const bf16x8*)&Al[row*72 + kh*32 + kg*8];
      }
      #pragma unroll
      for (int nf = 0; nf < 4; ++nf) {
        int nl = wn*64 + nf*16 + lane15;
        int jj = kh*4 + kg;
        bfr[nf] = *(const bf16x8*)&Bl[nl*64 + ((jj ^ (nl & 7)) << 3)];
      }
      #pragma unroll
      for (int mf = 0; mf < 4; ++mf)
        #pragma unroll
        for (int nf = 0; nf < 4; ++nf)
          acc[mf][nf] = __builtin_amdgcn_mfma_f32_16x16x32_bf16(af[mf], bfr[nf], acc[mf][nf], 0, 0, 0);
    }
    __syncthreads();
  }

  int bidx = m0 >> 11;
  float dpv[4], vwv[4];
  #pragma unroll
  for (int nf = 0; nf < 4; ++nf) {
    int n = n0 + wn*64 + nf*16 + lane15;
    dpv[nf] = dpb[bidx*HD + n];
    vwv[nf] = vw[n];
  }
  if (tid < 128) red[tid] = 0.0f;
  __syncthreads();
  #pragma unroll
  for (int mf = 0; mf < 4; ++mf) {
    #pragma unroll
    for (int r = 0; r < 4; ++r) {
      float s = 0.0f;
      #pragma unroll
      for (int nf = 0; nf < 4; ++nf) {
        float x = acc[mf][nf][r] + dpv[nf];
        s += tanh_fast(x) * vwv[nf];
      }
      s += __shfl_xor(s, 1); s += __shfl_xor(s, 2);
      s += __shfl_xor(s, 4); s += __shfl_xor(s, 8);
      if (lane15 == 0) atomicAdd(&red[wm*64 + mf*16 + kg*4 + r], s);
    }
  }
  __syncthreads();
  if (tid < 128) atomicAdd(&logits[m0 + tid], red[tid]);
}

// ---------------------------------------------------------------------------
// Kernel 4: masked softmax over S per batch row.  mask==1 -> -1e10
// ---------------------------------------------------------------------------
__global__ void softmax_k(const float* __restrict__ logits, const int* __restrict__ mask,
                          float* __restrict__ out) {
  __shared__ float smax[4];
  __shared__ float ssum[4];
  int tid = threadIdx.x, lane = tid & 63, wid = tid >> 6;
  int b = blockIdx.x;
  const float* lg = logits + b*SS;
  const int*   mk = mask   + b*SS;
  f32x4 l0 = *(const f32x4*)(lg + tid*8);
  f32x4 l1 = *(const f32x4*)(lg + tid*8 + 4);
  i32x4 q0 = *(const i32x4*)(mk + tid*8);
  i32x4 q1 = *(const i32x4*)(mk + tid*8 + 4);
  float v[8];
  v[0] = (q0.x == 1) ? NEGV : l0.x;  v[1] = (q0.y == 1) ? NEGV : l0.y;
  v[2] = (q0.z == 1) ? NEGV : l0.z;  v[3] = (q0.w == 1) ? NEGV : l0.w;
  v[4] = (q1.x == 1) ? NEGV : l1.x;  v[5] = (q1.y == 1) ? NEGV : l1.y;
  v[6] = (q1.z == 1) ? NEGV : l1.z;  v[7] = (q1.w == 1) ? NEGV : l1.w;
  float mx = v[0];
  #pragma unroll
  for (int i = 1; i < 8; ++i) mx = fmaxf(mx, v[i]);
  #pragma unroll
  for (int m = 1; m <= 32; m <<= 1) mx = fmaxf(mx, __shfl_xor(mx, m));
  if (lane == 0) smax[wid] = mx;
  __syncthreads();
  mx = fmaxf(fmaxf(smax[0], smax[1]), fmaxf(smax[2], smax[3]));
  float s = 0.0f;
  #pragma unroll
  for (int i = 0; i < 8; ++i) { v[i] = __expf(v[i] - mx); s += v[i]; }
  #pragma unroll
  for (int m = 1; m <= 32; m <<= 1) s += __shfl_xor(s, m);
  if (lane == 0) ssum[wid] = s;
  __syncthreads();
  s = ssum[0] + ssum[1] + ssum[2] + ssum[3];
  float inv = 1.0f / s;
  f32x4 o0 = {v[0]*inv, v[1]*inv, v[2]*inv, v[3]*inv};
  f32x4 o1 = {v[4]*inv, v[5]*inv, v[6]*inv, v[7]*inv};
  *(f32x4*)(out + b*SS + tid*8)     = o0;
  *(f32x4*)(out + b*SS + tid*8 + 4) = o1;
}

// ---------------------------------------------------------------------------
extern "C" void kernel_launch(void* const* d_in, const int* in_sizes, int n_in,
                              void* d_out, int out_size, void* d_ws, size_t ws_size,
                              hipStream_t stream) {
  const float* dec   = (const float*)d_in[0];   // (B, H)
  const float* enc   = (const float*)d_in[1];   // (B, S, H)
  const int*   mask  = (const int*)  d_in[2];   // (B, S)
  const float* Wattn = (const float*)d_in[3];   // (2H, H)
  const float* battn = (const float*)d_in[4];   // (H)
  const float* vw    = (const float*)d_in[5];   // (H)
  float* out = (float*)d_out;

  const size_t EBF_BYTES = (size_t)MT * HD * 2;             // 268435456
  const size_t FAST_NEED = EBF_BYTES + (2u<<20) + (256u<<10) + (512u<<10);

  char* ws = (char*)d_ws;
  if (ws_size >= FAST_NEED) {
    __hip_bfloat16* ebf = (__hip_bfloat16*)ws;
    __hip_bfloat16* wet = (__hip_bfloat16*)(ws + EBF_BYTES);
    float* dpb    = (float*)(ws + EBF_BYTES + (2u<<20));
    float* logits = (float*)(ws + EBF_BYTES + (2u<<20) + (256u<<10));

    prep_all<<<16384 + 1280, 256, 0, stream>>>(16384, enc, ebf, Wattn, wet,
                                               dec, battn, dpb, logits);
    gemm_fused_8ph<<<2048, 512, 0, stream>>>(ebf, wet, dpb, vw, logits);
    softmax_k<<<BB, 256, 0, stream>>>(logits, mask, out);
  } else {
    __hip_bfloat16* wet = (__hip_bfloat16*)ws;
    float* dpb    = (float*)(ws + (2u<<20));
    float* logits = (float*)(ws + (2u<<20) + (256u<<10));

    prep_all<<<1280, 256, 0, stream>>>(0, nullptr, nullptr, Wattn, wet,
                                       dec, battn, dpb, logits);
    gemm_fused_f32<<<8192, 256, 0, stream>>>(enc, wet, dpb, vw, logits);
    softmax_k<<<BB, 256, 0, stream>>>(logits, mask, out);
  }
}